// Round 2
// baseline (618.602 us; speedup 1.0000x reference)
//
#include <hip/hip_runtime.h>
#include <hip/hip_bf16.h>

// ---------------------------------------------------------------------------
// Shapes: x (N=64, C=256, T=300, V=17) fp32.  Output fp32, same shape.
// PARTS: each joint v belongs to exactly one part p(v):
//   v 0-4 -> p0 ; v 5,7,9 -> p1 ; v 6,8,10 -> p2 ; v 11,13,15 -> p3 ; v 12,14,16 -> p4
// ---------------------------------------------------------------------------

// ---- fold BN params into scale/bias ---------------------------------------
__global__ void fold_kernel(
    const float* __restrict__ part_b, const float* __restrict__ pbn_g,
    const float* __restrict__ pbn_b,  const float* __restrict__ pbn_m,
    const float* __restrict__ pbn_v,
    const float* __restrict__ fc1_b,  const float* __restrict__ fbn_g,
    const float* __restrict__ fbn_b,  const float* __restrict__ fbn_m,
    const float* __restrict__ fbn_v,
    const float* __restrict__ bn_g,   const float* __restrict__ bn_b,
    const float* __restrict__ bn_m,   const float* __restrict__ bn_v,
    float* __restrict__ ps, float* __restrict__ pb,
    float* __restrict__ fs, float* __restrict__ fb,
    float* __restrict__ cs, float* __restrict__ cb)
{
    int tid = threadIdx.x;                      // 320 threads
    if (tid < 320) {
        float s = pbn_g[tid] * rsqrtf(pbn_v[tid] + 1e-5f);
        ps[tid] = s;
        pb[tid] = part_b[tid] * s + pbn_b[tid] - pbn_m[tid] * s;
    }
    if (tid < 64) {
        float s = fbn_g[tid] * rsqrtf(fbn_v[tid] + 1e-5f);
        fs[tid] = s;
        fb[tid] = fc1_b[tid] * s + fbn_b[tid] - fbn_m[tid] * s;
    }
    if (tid < 256) {
        float s = bn_g[tid] * rsqrtf(bn_v[tid] + 1e-5f);
        cs[tid] = s;
        cb[tid] = bn_b[tid] - bn_m[tid] * s;
    }
}

// ---- transpose part_w [5][64][256] -> wt [5][256][64] (coalesced q reads) --
__global__ void transpose_w(const float* __restrict__ pw, float* __restrict__ wt)
{
    int i = blockIdx.x * 256 + threadIdx.x;
    if (i < 5 * 64 * 256) {
        int p = i >> 14;
        int r = i & 16383;
        int q = r >> 8;          // 0..63
        int c = r & 255;         // 0..255
        wt[(p << 14) + (c << 6) + q] = pw[i];
    }
}

// ---- pass 1: part conv + BN + ReLU + mean-pool into pooled[n][q] ----------
// grid = 64 n * 19 t-chunks; block = 256 (4 waves).
// wave w owns t = tb + w*4 + {0..3}; lane (tid&63) owns q.
__global__ __launch_bounds__(256) void part_pool_kernel(
    const float* __restrict__ x, const float* __restrict__ wt,
    const float* __restrict__ ps, const float* __restrict__ pb,
    float* __restrict__ pooled)
{
    constexpr int PV[17]  = {0,0,0,0,0,1,2,1,2,1,2,3,4,3,4,3,4};
    constexpr float COEF[5] = {1.f/1500.f, 1.f/900.f, 1.f/900.f, 1.f/900.f, 1.f/900.f};

    __shared__ float xs[32][16][20];   // [c_local][t_local][v padded] = 40 KB

    const int blk = blockIdx.x;
    const int n   = blk / 19;
    const int tb  = (blk % 19) * 16;
    const int tid = threadIdx.x;
    const int q   = tid & 63;
    const int w   = tid >> 6;

    float acc[4][17];
    #pragma unroll
    for (int i = 0; i < 4; ++i)
        #pragma unroll
        for (int v = 0; v < 17; ++v) acc[i][v] = 0.f;

    const int srow = tid >> 3;   // 0..31  (c_local row to stage)
    const int ssub = tid & 7;    // 0..7   (which 34-float slice of the 272)

    for (int cc = 0; cc < 256; cc += 32) {
        __syncthreads();
        // stage x[n, cc+row, tb..tb+15, 0..16] -> xs (272 floats per row)
        const float* gsrc = x + ((size_t)(n * 256 + cc + srow) * 300 + tb) * 17;
        #pragma unroll
        for (int k = 0; k < 34; ++k) {
            // f = ssub*34 + k ; 34 = 2*17 so tl = 2*ssub + (k>=17), v = k mod 17
            const int tl = 2 * ssub + (k >= 17 ? 1 : 0);
            const int v  = (k >= 17) ? (k - 17) : k;
            float val = 0.f;
            if (tb + tl < 300) val = gsrc[ssub * 34 + k];
            xs[srow][tl][v] = val;
        }
        __syncthreads();

        for (int cl = 0; cl < 32; ++cl) {
            const int cg = cc + cl;
            float wp[5];
            #pragma unroll
            for (int p = 0; p < 5; ++p)
                wp[p] = wt[(p << 14) + (cg << 6) + q];   // coalesced, L2-resident

            #pragma unroll
            for (int ti = 0; ti < 4; ++ti) {
                const float* xr = &xs[cl][(w << 2) + ti][0];  // wave-uniform -> LDS broadcast
                float xv[17];
                float4 t0 = *(const float4*)(xr);
                float4 t1 = *(const float4*)(xr + 4);
                float4 t2 = *(const float4*)(xr + 8);
                float4 t3 = *(const float4*)(xr + 12);
                xv[0]=t0.x; xv[1]=t0.y; xv[2]=t0.z;  xv[3]=t0.w;
                xv[4]=t1.x; xv[5]=t1.y; xv[6]=t1.z;  xv[7]=t1.w;
                xv[8]=t2.x; xv[9]=t2.y; xv[10]=t2.z; xv[11]=t2.w;
                xv[12]=t3.x; xv[13]=t3.y; xv[14]=t3.z; xv[15]=t3.w;
                xv[16] = xr[16];
                #pragma unroll
                for (int v = 0; v < 17; ++v)
                    acc[ti][v] = fmaf(wp[PV[v]], xv[v], acc[ti][v]);
            }
        }
    }

    // epilogue: BN + ReLU + coef, reduce over this thread's (t, v), atomic into pooled
    float s5[5], b5[5];
    #pragma unroll
    for (int p = 0; p < 5; ++p) { s5[p] = ps[(p << 6) + q]; b5[p] = pb[(p << 6) + q]; }

    float sum = 0.f;
    #pragma unroll
    for (int ti = 0; ti < 4; ++ti) {
        const int t = tb + (w << 2) + ti;
        if (t < 300) {
            #pragma unroll
            for (int v = 0; v < 17; ++v) {
                const int p = PV[v];
                float y = fmaf(s5[p], acc[ti][v], b5[p]);
                sum = fmaf(fmaxf(y, 0.f), COEF[p], sum);
            }
        }
    }
    atomicAdd(&pooled[(n << 6) + q], sum);
}

// ---- pass 2: FC1+BN+ReLU, FC2, softmax over 5 parts -> att[n][c][p] -------
__global__ __launch_bounds__(256) void fc_att_kernel(
    const float* __restrict__ pooled, const float* __restrict__ fc1_w,
    const float* __restrict__ fs, const float* __restrict__ fb,
    const float* __restrict__ fc2_w, const float* __restrict__ fc2_b,
    float* __restrict__ att)
{
    __shared__ float pl[64];
    __shared__ float hl[64];
    const int n = blockIdx.x;
    const int tid = threadIdx.x;

    if (tid < 64) pl[tid] = pooled[(n << 6) + tid];
    __syncthreads();
    if (tid < 64) {
        float d = 0.f;
        #pragma unroll
        for (int j = 0; j < 64; ++j) d = fmaf(pl[j], fc1_w[(tid << 6) + j], d);
        hl[tid] = fmaxf(fmaf(d, fs[tid], fb[tid]), 0.f);
    }
    __syncthreads();

    const int c = tid;  // 0..255
    float z[5];
    #pragma unroll
    for (int p = 0; p < 5; ++p) {
        const float* wrow = fc2_w + ((size_t)(c * 5 + p) << 6);
        float d = fc2_b[c * 5 + p];
        #pragma unroll
        for (int i = 0; i < 64; ++i) d = fmaf(hl[i], wrow[i], d);
        z[p] = d;
    }
    float m = z[0];
    #pragma unroll
    for (int p = 1; p < 5; ++p) m = fmaxf(m, z[p]);
    float e[5], ssum = 0.f;
    #pragma unroll
    for (int p = 0; p < 5; ++p) { e[p] = __expf(z[p] - m); ssum += e[p]; }
    const float inv = 1.f / ssum;
    #pragma unroll
    for (int p = 0; p < 5; ++p)
        att[((size_t)((n << 8) + c)) * 5 + p] = e[p] * inv;
}

// ---- pass 3: out = relu( x*(att*cs + 1) + cb ), fp32 store ----------------
__global__ __launch_bounds__(256) void apply_att_kernel(
    const float* __restrict__ x, const float* __restrict__ att,
    const float* __restrict__ cs, const float* __restrict__ cb,
    float* __restrict__ out)
{
    const unsigned total = 64u * 256u * 300u * 17u;   // 83,558,400
    const unsigned stride = gridDim.x * blockDim.x;
    for (unsigned i = blockIdx.x * blockDim.x + threadIdx.x; i < total; i += stride) {
        const unsigned v  = i % 17u;
        const unsigned nc = i / 5100u;       // n*256 + c
        const unsigned c  = nc & 255u;
        const int p = (v < 5u) ? 0 : ((v < 11u) ? (2 - (int)(v & 1u)) : (4 - (int)(v & 1u)));
        const float a  = att[nc * 5u + p];
        const float xv = x[i];
        const float r  = fmaf(xv, fmaf(a, cs[c], 1.f), cb[c]);
        out[i] = fmaxf(r, 0.f);
    }
}

// ---------------------------------------------------------------------------
extern "C" void kernel_launch(void* const* d_in, const int* in_sizes, int n_in,
                              void* d_out, int out_size, void* d_ws, size_t ws_size,
                              hipStream_t stream)
{
    const float* x      = (const float*)d_in[0];
    const float* part_w = (const float*)d_in[1];
    const float* part_b = (const float*)d_in[2];
    const float* pbn_g  = (const float*)d_in[3];
    const float* pbn_b  = (const float*)d_in[4];
    const float* pbn_m  = (const float*)d_in[5];
    const float* pbn_v  = (const float*)d_in[6];
    const float* fc1_w  = (const float*)d_in[7];
    const float* fc1_b  = (const float*)d_in[8];
    const float* fbn_g  = (const float*)d_in[9];
    const float* fbn_b  = (const float*)d_in[10];
    const float* fbn_m  = (const float*)d_in[11];
    const float* fbn_v  = (const float*)d_in[12];
    const float* fc2_w  = (const float*)d_in[13];
    const float* fc2_b  = (const float*)d_in[14];
    const float* bn_g   = (const float*)d_in[15];
    const float* bn_b   = (const float*)d_in[16];
    const float* bn_m   = (const float*)d_in[17];
    const float* bn_v   = (const float*)d_in[18];

    float* ws     = (float*)d_ws;
    float* pooled = ws;             // 4096
    float* att    = ws + 4096;      // 81920
    float* ps     = ws + 86016;     // 320
    float* pbias  = ws + 86336;     // 320
    float* fs     = ws + 86656;     // 64
    float* fb     = ws + 86720;     // 64
    float* cs     = ws + 86784;     // 256
    float* cb     = ws + 87040;     // 256
    float* wt     = ws + 87296;     // 81920   (total 169216 floats = 677 KB)

    hipMemsetAsync(pooled, 0, 4096 * sizeof(float), stream);  // atomics accumulate

    fold_kernel<<<1, 320, 0, stream>>>(part_b, pbn_g, pbn_b, pbn_m, pbn_v,
                                       fc1_b, fbn_g, fbn_b, fbn_m, fbn_v,
                                       bn_g, bn_b, bn_m, bn_v,
                                       ps, pbias, fs, fb, cs, cb);
    transpose_w<<<320, 256, 0, stream>>>(part_w, wt);
    part_pool_kernel<<<64 * 19, 256, 0, stream>>>(x, wt, ps, pbias, pooled);
    fc_att_kernel<<<64, 256, 0, stream>>>(pooled, fc1_w, fs, fb, fc2_w, fc2_b, att);
    apply_att_kernel<<<16384, 256, 0, stream>>>(x, att, cs, cb, (float*)d_out);
}

// Round 3
// 279.947 us; speedup vs baseline: 2.2097x; 2.2097x over previous
//
#include <hip/hip_runtime.h>
#include <hip/hip_bf16.h>

// ---------------------------------------------------------------------------
// x (N=64, C=256, T=300, V=17) fp32.  Output fp32 same shape.
// v->part: 0-4 -> p0 ; 5,7,9 -> p1 ; 6,8,10 -> p2 ; 11,13,15 -> p3 ; 12,14,16 -> p4
// Pass1: per (n, 16-t block): rows = 272 (t,v) pairs grouped by part into
// 17 M-tiles of 16; GEMM vs W[p] (64q x 256c) via mfma_f32_16x16x32_bf16;
// BN+ReLU+mean epilogue -> pooled[n][q] atomics.
// ---------------------------------------------------------------------------

typedef __attribute__((ext_vector_type(8))) short short8;
typedef __attribute__((ext_vector_type(4))) float f32x4;
typedef float f4u __attribute__((ext_vector_type(4), aligned(4)));

__device__ __forceinline__ unsigned short f2bf(float f) {
    unsigned int u = __float_as_uint(f);
    u = (u + 0x7FFFu + ((u >> 16) & 1u)) >> 16;   // RNE
    return (unsigned short)u;
}

// ---- fold BN params into scale/bias ---------------------------------------
__global__ void fold_kernel(
    const float* __restrict__ part_b, const float* __restrict__ pbn_g,
    const float* __restrict__ pbn_b,  const float* __restrict__ pbn_m,
    const float* __restrict__ pbn_v,
    const float* __restrict__ fc1_b,  const float* __restrict__ fbn_g,
    const float* __restrict__ fbn_b,  const float* __restrict__ fbn_m,
    const float* __restrict__ fbn_v,
    const float* __restrict__ bn_g,   const float* __restrict__ bn_b,
    const float* __restrict__ bn_m,   const float* __restrict__ bn_v,
    float* __restrict__ ps, float* __restrict__ pb,
    float* __restrict__ fs, float* __restrict__ fb,
    float* __restrict__ cs, float* __restrict__ cb)
{
    int tid = threadIdx.x;
    if (tid < 320) {
        float s = pbn_g[tid] * rsqrtf(pbn_v[tid] + 1e-5f);
        ps[tid] = s;
        pb[tid] = part_b[tid] * s + pbn_b[tid] - pbn_m[tid] * s;
    }
    if (tid < 64) {
        float s = fbn_g[tid] * rsqrtf(fbn_v[tid] + 1e-5f);
        fs[tid] = s;
        fb[tid] = fc1_b[tid] * s + fbn_b[tid] - fbn_m[tid] * s;
    }
    if (tid < 256) {
        float s = bn_g[tid] * rsqrtf(bn_v[tid] + 1e-5f);
        cs[tid] = s;
        cb[tid] = bn_b[tid] - bn_m[tid] * s;
    }
}

// ---- convert part_w [5][64][256] fp32 -> bf16 (same layout) ---------------
__global__ void conv_w_kernel(const float* __restrict__ pw, unsigned short* __restrict__ wq)
{
    int i = blockIdx.x * 256 + threadIdx.x;
    if (i < 5 * 64 * 256) wq[i] = f2bf(pw[i]);
}

// ---- pass 1: MFMA part conv + BN + ReLU + mean-pool -----------------------
// grid = 64 n * 19 t-chunks; block 256 = 4 waves; wave = one 16-q tile.
__global__ __launch_bounds__(256) void part_pool_kernel(
    const float* __restrict__ x, const unsigned short* __restrict__ wq,
    const float* __restrict__ ps, const float* __restrict__ pb,
    float* __restrict__ pooled)
{
    // row(t,v) = ROWC[v] + t*CNTV[v];  272 rows grouped: p0:[0,80) p1:[80,128)
    // p2:[128,176) p3:[176,224) p4:[224,272)
    constexpr int ROWC[17] = {0,1,2,3,4, 80,128, 81,129, 82,130, 176,224, 177,225, 178,226};
    constexpr int CNTV[17] = {5,5,5,5,5, 3,3,3,3,3,3, 3,3,3,3,3,3};
    constexpr int PMAP[17] = {0,0,0,0,0, 1,1,1, 2,2,2, 3,3,3, 4,4,4};
    constexpr int BASE[5]  = {0,80,128,176,224};
    constexpr int CNT[5]   = {5,3,3,3,3};
    constexpr float COEF[5] = {1.f/1500.f, 1.f/900.f, 1.f/900.f, 1.f/900.f, 1.f/900.f};

    __shared__ short Xs[272 * 64];   // [row][c] bf16, 128B rows, XOR-swizzled: 34816 B

    const int blk = blockIdx.x;
    const int n   = blk / 19;
    const int tb  = (blk % 19) * 16;
    const int tid = threadIdx.x;
    const int lane = tid & 63;
    const int wv   = tid >> 6;       // q-tile 0..3
    const int r15  = lane & 15;
    const int g    = lane >> 4;      // 0..3
    const int key  = (r15 & 7) << 4; // A/B-read swizzle key (row&7 == r15&7)

    // staging mapping: c-pair + t-pair per thread
    const int cp  = tid & 31;        // c_local = 2*cp, 2*cp+1
    const int oct = tid >> 5;        // t_local = 2*oct, 2*oct+1

    f32x4 acc[17];
    #pragma unroll
    for (int m = 0; m < 17; ++m) acc[m] = (f32x4){0.f, 0.f, 0.f, 0.f};

    for (int cc = 0; cc < 256; cc += 64) {
        __syncthreads();   // protect Xs from overwrite while prev chunk computes
        // ---- stage x[n, cc+2cp..+1, tb+2oct..+1, 0..16] -> Xs[row][c] bf16
        #pragma unroll
        for (int dt = 0; dt < 2; ++dt) {
            const int tl = 2 * oct + dt;
            const int tg = tb + tl;
            float r0[17], r1[17];
            if (tg < 300) {
                const float* g0 = x + ((size_t)(n * 256 + cc + 2 * cp) * 300 + tg) * 17;
                const float* g1 = g0 + 300 * 17;
                f4u a0 = *(const f4u*)(g0);     f4u b0 = *(const f4u*)(g1);
                f4u a1 = *(const f4u*)(g0 + 4); f4u b1 = *(const f4u*)(g1 + 4);
                f4u a2 = *(const f4u*)(g0 + 8); f4u b2 = *(const f4u*)(g1 + 8);
                f4u a3 = *(const f4u*)(g0 +12); f4u b3 = *(const f4u*)(g1 +12);
                #pragma unroll
                for (int j = 0; j < 4; ++j) {
                    r0[j]    = a0[j]; r1[j]    = b0[j];
                    r0[4+j]  = a1[j]; r1[4+j]  = b1[j];
                    r0[8+j]  = a2[j]; r1[8+j]  = b2[j];
                    r0[12+j] = a3[j]; r1[12+j] = b3[j];
                }
                r0[16] = g0[16]; r1[16] = g1[16];
            } else {
                #pragma unroll
                for (int v = 0; v < 17; ++v) { r0[v] = 0.f; r1[v] = 0.f; }
            }
            #pragma unroll
            for (int v = 0; v < 17; ++v) {
                const int row = ROWC[v] + tl * CNTV[v];
                unsigned int pk = (unsigned int)f2bf(r0[v]) | ((unsigned int)f2bf(r1[v]) << 16);
                const int off = row * 128 + ((cp * 4) ^ ((row & 7) << 4));
                *(unsigned int*)((char*)Xs + off) = pk;
            }
        }
        __syncthreads();

        // ---- compute: 2 k-steps of 32, 17 M-tiles, B from global (L2) -----
        #pragma unroll
        for (int kk = 0; kk < 2; ++kk) {
            short8 bfr[5];
            #pragma unroll
            for (int p = 0; p < 5; ++p) {
                const int widx = ((p * 64 + wv * 16 + r15) << 8) + cc + kk * 32 + g * 8;
                bfr[p] = *(const short8*)(wq + widx);
            }
            const int cofs = ((kk * 64 + g * 16) ^ key);
            #pragma unroll
            for (int m = 0; m < 17; ++m) {
                short8 a = *(const short8*)((const char*)Xs + (m * 16 + r15) * 128 + cofs);
                acc[m] = __builtin_amdgcn_mfma_f32_16x16x32_bf16(a, bfr[PMAP[m]], acc[m], 0, 0, 0);
            }
        }
    }

    // ---- epilogue: D[row][q]: q = wv*16 + r15 (col=lane&15), row = m*16+g*4+rg
    const int q = wv * 16 + r15;
    float s5[5], b5[5];
    #pragma unroll
    for (int p = 0; p < 5; ++p) { s5[p] = ps[(p << 6) + q]; b5[p] = pb[(p << 6) + q]; }

    float sum = 0.f;
    #pragma unroll
    for (int m = 0; m < 17; ++m) {
        const int p = PMAP[m];
        #pragma unroll
        for (int rg = 0; rg < 4; ++rg) {
            const int row = m * 16 + g * 4 + rg;
            const int tl  = (row - BASE[p]) / CNT[p];
            if (tb + tl < 300) {
                float y = fmaf(s5[p], acc[m][rg], b5[p]);
                sum = fmaf(fmaxf(y, 0.f), COEF[p], sum);
            }
        }
    }
    sum += __shfl_xor(sum, 16);
    sum += __shfl_xor(sum, 32);
    if (g == 0) atomicAdd(&pooled[(n << 6) + q], sum);
}

// ---- pass 2: FC1+BN+ReLU, FC2, softmax over 5 parts -> att[n][c][p] -------
__global__ __launch_bounds__(256) void fc_att_kernel(
    const float* __restrict__ pooled, const float* __restrict__ fc1_w,
    const float* __restrict__ fs, const float* __restrict__ fb,
    const float* __restrict__ fc2_w, const float* __restrict__ fc2_b,
    float* __restrict__ att)
{
    __shared__ float pl[64];
    __shared__ float hl[64];
    const int n = blockIdx.x;
    const int tid = threadIdx.x;

    if (tid < 64) pl[tid] = pooled[(n << 6) + tid];
    __syncthreads();
    if (tid < 64) {
        float d = 0.f;
        #pragma unroll
        for (int j = 0; j < 64; ++j) d = fmaf(pl[j], fc1_w[(tid << 6) + j], d);
        hl[tid] = fmaxf(fmaf(d, fs[tid], fb[tid]), 0.f);
    }
    __syncthreads();

    const int c = tid;  // 0..255
    float z[5];
    #pragma unroll
    for (int p = 0; p < 5; ++p) {
        const float* wrow = fc2_w + ((size_t)(c * 5 + p) << 6);
        float d = fc2_b[c * 5 + p];
        #pragma unroll
        for (int i = 0; i < 64; ++i) d = fmaf(hl[i], wrow[i], d);
        z[p] = d;
    }
    float m = z[0];
    #pragma unroll
    for (int p = 1; p < 5; ++p) m = fmaxf(m, z[p]);
    float e[5], ssum = 0.f;
    #pragma unroll
    for (int p = 0; p < 5; ++p) { e[p] = __expf(z[p] - m); ssum += e[p]; }
    const float inv = 1.f / ssum;
    #pragma unroll
    for (int p = 0; p < 5; ++p)
        att[((size_t)((n << 8) + c)) * 5 + p] = e[p] * inv;
}

// ---- pass 3: out = relu( x*(att*cs + 1) + cb ), float4 vectorized ---------
// block = one (n,c) plane: 5100 floats = 1275 float4 (16B aligned).
__global__ __launch_bounds__(256) void apply_att_kernel(
    const float* __restrict__ x, const float* __restrict__ att,
    const float* __restrict__ cs, const float* __restrict__ cb,
    float* __restrict__ out)
{
    __shared__ float mult[17];
    const int nc  = blockIdx.x;          // n*256 + c
    const int c   = nc & 255;
    const int tid = threadIdx.x;

    if (tid < 17) {
        const int v = tid;
        const int p = (v < 5) ? 0 : ((v < 11) ? (2 - (v & 1)) : (4 - (v & 1)));
        mult[v] = fmaf(att[(size_t)nc * 5 + p], cs[c], 1.0f);
    }
    __syncthreads();

    const float cbc = cb[c];
    const float4* xp = (const float4*)(x + (size_t)nc * 5100);
    float4* op = (float4*)(out + (size_t)nc * 5100);

    for (int f = tid; f < 1275; f += 256) {
        float4 xv = xp[f];
        const int v0 = (4 * f) % 17;
        float o[4];
        const float xi[4] = {xv.x, xv.y, xv.z, xv.w};
        #pragma unroll
        for (int j = 0; j < 4; ++j) {
            int vj = v0 + j; if (vj >= 17) vj -= 17;
            o[j] = fmaxf(fmaf(xi[j], mult[vj], cbc), 0.f);
        }
        float4 ov; ov.x = o[0]; ov.y = o[1]; ov.z = o[2]; ov.w = o[3];
        op[f] = ov;
    }
}

// ---------------------------------------------------------------------------
extern "C" void kernel_launch(void* const* d_in, const int* in_sizes, int n_in,
                              void* d_out, int out_size, void* d_ws, size_t ws_size,
                              hipStream_t stream)
{
    const float* x      = (const float*)d_in[0];
    const float* part_w = (const float*)d_in[1];
    const float* part_b = (const float*)d_in[2];
    const float* pbn_g  = (const float*)d_in[3];
    const float* pbn_b  = (const float*)d_in[4];
    const float* pbn_m  = (const float*)d_in[5];
    const float* pbn_v  = (const float*)d_in[6];
    const float* fc1_w  = (const float*)d_in[7];
    const float* fc1_b  = (const float*)d_in[8];
    const float* fbn_g  = (const float*)d_in[9];
    const float* fbn_b  = (const float*)d_in[10];
    const float* fbn_m  = (const float*)d_in[11];
    const float* fbn_v  = (const float*)d_in[12];
    const float* fc2_w  = (const float*)d_in[13];
    const float* fc2_b  = (const float*)d_in[14];
    const float* bn_g   = (const float*)d_in[15];
    const float* bn_b   = (const float*)d_in[16];
    const float* bn_m   = (const float*)d_in[17];
    const float* bn_v   = (const float*)d_in[18];

    float* ws     = (float*)d_ws;
    float* pooled = ws;             // 4096
    float* att    = ws + 4096;      // 81920
    float* ps     = ws + 86016;     // 320
    float* pbias  = ws + 86336;     // 320
    float* fs     = ws + 86656;     // 64
    float* fb     = ws + 86720;     // 64
    float* cs     = ws + 86784;     // 256
    float* cb     = ws + 87040;     // 256
    unsigned short* wq = (unsigned short*)(ws + 87296);  // 81920 bf16 (16B-aligned)

    hipMemsetAsync(pooled, 0, 4096 * sizeof(float), stream);

    fold_kernel<<<1, 320, 0, stream>>>(part_b, pbn_g, pbn_b, pbn_m, pbn_v,
                                       fc1_b, fbn_g, fbn_b, fbn_m, fbn_v,
                                       bn_g, bn_b, bn_m, bn_v,
                                       ps, pbias, fs, fb, cs, cb);
    conv_w_kernel<<<320, 256, 0, stream>>>(part_w, wq);
    part_pool_kernel<<<64 * 19, 256, 0, stream>>>(x, wq, ps, pbias, pooled);
    fc_att_kernel<<<64, 256, 0, stream>>>(pooled, fc1_w, fs, fb, fc2_w, fc2_b, att);
    apply_att_kernel<<<16384, 256, 0, stream>>>(x, att, cs, cb, (float*)d_out);
}